// Round 3
// baseline (7944.619 us; speedup 1.0000x reference)
//
#include <hip/hip_runtime.h>
#include <hip/hip_bf16.h>

#define N_NODES 100000
#define N_EDGES 1600000
#define N_EL    200000
// D_IN = D_HID = 128; layer-3 output D = 64.
// Inputs: f32 floats, int32 indices. Output: f32 (reference returns float32;
// the test's "bf16" label is the comparison mode, not the buffer dtype).

// ---------------- degree / norm ----------------
__global__ void k_init_deg(float* deg) {
    int i = blockIdx.x * blockDim.x + threadIdx.x;
    if (i < N_NODES) deg[i] = 1.0f;   // self-loop
}

__global__ void k_count_deg(const int* __restrict__ dst, float* __restrict__ deg) {
    int e = blockIdx.x * blockDim.x + threadIdx.x;
    if (e < N_EDGES) atomicAdd(&deg[dst[e]], 1.0f);
}

__global__ void k_dinv(float* deg) {
    int i = blockIdx.x * blockDim.x + threadIdx.x;
    if (i < N_NODES) deg[i] = 1.0f / sqrtf(deg[i]);   // deg >= 1
}

// ---------------- GEMM: C[N x D] = A[N x 128] * W[128 x D], fp32 ----------------
template <int D>
__global__ void k_gemm(const float* __restrict__ A, const float* __restrict__ W,
                       float* __restrict__ C) {
    unsigned gid = blockIdx.x * blockDim.x + threadIdx.x;
    if (gid >= (unsigned)N_NODES * D) return;
    unsigned n = gid / D;
    unsigned d = gid % D;
    const float* a = A + (size_t)n * 128;
    float acc = 0.0f;
#pragma unroll 8
    for (int k = 0; k < 128; ++k) {
        acc += a[k] * W[k * D + d];
    }
    C[gid] = acc;
}

// ---------------- edge scatter: agg[dst] += t[src] * dinv[src]*dinv[dst] ----------------
template <int D>
__global__ void k_scatter(const int* __restrict__ src, const int* __restrict__ dst,
                          const float* __restrict__ dinv, const float* __restrict__ t,
                          float* __restrict__ agg) {
    const int C4 = D / 4;
    unsigned gid = blockIdx.x * blockDim.x + threadIdx.x;
    if (gid >= (unsigned)N_EDGES * C4) return;
    unsigned e = gid / C4;
    unsigned c = gid % C4;
    int s = src[e], d = dst[e];
    float nrm = dinv[s] * dinv[d];
    float4 v = *(const float4*)(t + (size_t)s * D + c * 4);
    float* out = agg + (size_t)d * D + c * 4;
    atomicAdd(out + 0, v.x * nrm);
    atomicAdd(out + 1, v.y * nrm);
    atomicAdd(out + 2, v.z * nrm);
    atomicAdd(out + 3, v.w * nrm);
}

// ---------------- finalize: agg = [relu](agg + t*dinv^2 + b) ----------------
template <int D, bool RELU>
__global__ void k_finalize(float* __restrict__ agg, const float* __restrict__ t,
                           const float* __restrict__ dinv, const float* __restrict__ b) {
    unsigned gid = blockIdx.x * blockDim.x + threadIdx.x;
    if (gid >= (unsigned)N_NODES * D) return;
    unsigned n = gid / D;
    unsigned d = gid % D;
    float di = dinv[n];
    float v = agg[gid] + t[gid] * di * di + b[d];
    if (RELU) v = fmaxf(v, 0.0f);
    agg[gid] = v;
}

// ---------------- decode: out[e] = dot(z[a], z[b]) over 64 dims, f32 store ----------------
__global__ void k_decode(const int* __restrict__ eli, const float* __restrict__ z,
                         float* __restrict__ out) {
    int e = blockIdx.x * blockDim.x + threadIdx.x;
    if (e >= N_EL) return;
    int a = eli[e];
    int b = eli[N_EL + e];
    const float4* za = (const float4*)(z + (size_t)a * 64);
    const float4* zb = (const float4*)(z + (size_t)b * 64);
    float acc = 0.0f;
#pragma unroll
    for (int i = 0; i < 16; ++i) {
        float4 x = za[i], y = zb[i];
        acc += x.x * y.x + x.y * y.y + x.z * y.z + x.w * y.w;
    }
    out[e] = acc;
}

extern "C" void kernel_launch(void* const* d_in, const int* in_sizes, int n_in,
                              void* d_out, int out_size, void* d_ws, size_t ws_size,
                              hipStream_t stream) {
    const float* x   = (const float*)d_in[0];
    const int*   ei  = (const int*)d_in[1];   // [2, E] row-major: src then dst
    const int*   eli = (const int*)d_in[2];   // [2, EL]
    const float* W1  = (const float*)d_in[3];
    const float* b1  = (const float*)d_in[4];
    const float* W2  = (const float*)d_in[5];
    const float* b2  = (const float*)d_in[6];
    const float* W3  = (const float*)d_in[7];
    const float* b3  = (const float*)d_in[8];
    float* out = (float*)d_out;

    const int* srcA = ei;
    const int* dstA = ei + N_EDGES;

    // workspace layout
    char* ws = (char*)d_ws;
    float* dinv = (float*)ws;                                   // N floats
    float* t    = (float*)(ws + (512u << 10));                  // N*128 f32
    float* agg  = (float*)(ws + (512u << 10) + (size_t)N_NODES * 128 * 4);  // N*128 f32

    const int B = 256;
    const int gN    = (N_NODES + B - 1) / B;
    const int gE    = (N_EDGES + B - 1) / B;
    const int gND   = (N_NODES * 128 + B - 1) / B;
    const int gND64 = (N_NODES * 64 + B - 1) / B;
    const int gS128 = (N_EDGES * 32 + B - 1) / B;
    const int gS64  = (N_EDGES * 16 + B - 1) / B;
    const int gEL   = (N_EL + B - 1) / B;

    // degrees -> dinv
    k_init_deg<<<gN, B, 0, stream>>>(dinv);
    k_count_deg<<<gE, B, 0, stream>>>(dstA, dinv);
    k_dinv<<<gN, B, 0, stream>>>(dinv);

    // layer 1: x @ W1 -> t ; scatter -> agg ; finalize(relu) in agg
    k_gemm<128><<<gND, B, 0, stream>>>(x, W1, t);
    hipMemsetAsync(agg, 0, (size_t)N_NODES * 128 * 4, stream);
    k_scatter<128><<<gS128, B, 0, stream>>>(srcA, dstA, dinv, t, agg);
    k_finalize<128, true><<<gND, B, 0, stream>>>(agg, t, dinv, b1);

    // layer 2: agg @ W2 -> t ; scatter -> agg ; finalize(relu)
    k_gemm<128><<<gND, B, 0, stream>>>(agg, W2, t);
    hipMemsetAsync(agg, 0, (size_t)N_NODES * 128 * 4, stream);
    k_scatter<128><<<gS128, B, 0, stream>>>(srcA, dstA, dinv, t, agg);
    k_finalize<128, true><<<gND, B, 0, stream>>>(agg, t, dinv, b2);

    // layer 3: agg @ W3 -> t(N x 64) ; scatter -> agg ; finalize (no relu) -> z
    k_gemm<64><<<gND64, B, 0, stream>>>(agg, W3, t);
    hipMemsetAsync(agg, 0, (size_t)N_NODES * 64 * 4, stream);
    k_scatter<64><<<gS64, B, 0, stream>>>(srcA, dstA, dinv, t, agg);
    k_finalize<64, false><<<gND64, B, 0, stream>>>(agg, t, dinv, b3);

    // decode
    k_decode<<<gEL, B, 0, stream>>>(eli, agg, out);
}

// Round 4
// 1500.837 us; speedup vs baseline: 5.2935x; 5.2935x over previous
//
#include <hip/hip_runtime.h>
#include <hip/hip_bf16.h>

#define N_NODES 100000
#define N_EDGES 1600000
#define N_EL    200000
// D_IN = D_HID = 128; layer-3 output D = 64.
// f32 inputs, int32 indices, f32 output.
//
// Strategy (round 4): CSR pull-gather (no atomics in aggregation).
//   t' = dinv .* (A @ W)        (dinv fused into GEMM epilogue)
//   out[d] = relu(dinv[d] * (sum_{s in N(d)} t'[s] + t'[d]) + b)

// ---------------- degree histogram (int) ----------------
__global__ void k_hist(const int* __restrict__ dst, int* __restrict__ degi) {
    int e = blockIdx.x * blockDim.x + threadIdx.x;
    if (e < N_EDGES) atomicAdd(&degi[dst[e]], 1);
}

__global__ void k_dinv(const int* __restrict__ degi, float* __restrict__ dinv) {
    int i = blockIdx.x * blockDim.x + threadIdx.x;
    if (i < N_NODES) dinv[i] = 1.0f / sqrtf((float)(degi[i] + 1));  // +1 self-loop
}

// ---------------- exclusive scan of degi -> rowptr (single block) ----------------
__global__ void k_scan_rowptr(const int* __restrict__ degi, int* __restrict__ rowptr) {
    const int T = 1024;
    __shared__ int partial[T];
    int tid = threadIdx.x;
    int chunk = (N_NODES + T - 1) / T;           // 98
    int start = tid * chunk;
    int end = min(start + chunk, N_NODES);
    int sum = 0;
    for (int i = start; i < end; ++i) sum += degi[i];
    partial[tid] = sum;
    __syncthreads();
    for (int off = 1; off < T; off <<= 1) {
        int v = (tid >= off) ? partial[tid - off] : 0;
        __syncthreads();
        partial[tid] += v;
        __syncthreads();
    }
    int run = (tid == 0) ? 0 : partial[tid - 1];
    for (int i = start; i < end; ++i) {
        rowptr[i] = run;
        run += degi[i];
    }
    if (tid == T - 1) rowptr[N_NODES] = run;
}

// ---------------- CSR fill: col[pos] = src ----------------
__global__ void k_fill(const int* __restrict__ src, const int* __restrict__ dst,
                       const int* __restrict__ rowptr, int* __restrict__ cursor,
                       int* __restrict__ col) {
    int e = blockIdx.x * blockDim.x + threadIdx.x;
    if (e >= N_EDGES) return;
    int d = dst[e];
    int pos = rowptr[d] + atomicAdd(&cursor[d], 1);
    col[pos] = src[e];
}

// ---------------- GEMM: C[n,:] = dinv[n] * (A[n,:128] @ W[128,D]) ----------------
// one thread = 4 consecutive outputs (float4)
template <int D>
__global__ void k_gemm4(const float* __restrict__ A, const float* __restrict__ W,
                        const float* __restrict__ dinv, float* __restrict__ C) {
    const int C4 = D / 4;
    unsigned gid = blockIdx.x * blockDim.x + threadIdx.x;
    if (gid >= (unsigned)N_NODES * C4) return;
    unsigned n = gid / C4;
    unsigned c = gid % C4;
    const float* a = A + (size_t)n * 128;
    const float4* W4 = (const float4*)W;   // [128][C4] float4 view
    float4 acc = make_float4(0.f, 0.f, 0.f, 0.f);
#pragma unroll 8
    for (int k = 0; k < 128; ++k) {
        float av = a[k];
        float4 w = W4[k * C4 + c];
        acc.x += av * w.x; acc.y += av * w.y;
        acc.z += av * w.z; acc.w += av * w.w;
    }
    float di = dinv[n];
    acc.x *= di; acc.y *= di; acc.z *= di; acc.w *= di;
    ((float4*)C)[gid] = acc;
}

// ---------------- gather, D=128: one wave per node, float2 per lane ----------------
template <bool RELU>
__global__ void k_gather128(const int* __restrict__ rowptr, const int* __restrict__ col,
                            const float* __restrict__ dinv, const float* __restrict__ t,
                            const float* __restrict__ b, float* __restrict__ outbuf) {
    unsigned wid = (blockIdx.x * blockDim.x + threadIdx.x) >> 6;   // node id
    int lane = threadIdx.x & 63;
    if (wid >= N_NODES) return;
    int beg = rowptr[wid], end = rowptr[wid + 1];
    const float2* T2 = (const float2*)t;
    float2 acc = T2[(size_t)wid * 64 + lane];    // self-loop term t'[n]
    for (int j = beg; j < end; ++j) {
        int s = col[j];                           // wave-uniform broadcast load
        float2 v = T2[(size_t)s * 64 + lane];     // 512B coalesced row read
        acc.x += v.x; acc.y += v.y;
    }
    float di = dinv[wid];
    float2 bb = ((const float2*)b)[lane];
    float ox = di * acc.x + bb.x;
    float oy = di * acc.y + bb.y;
    if (RELU) { ox = fmaxf(ox, 0.f); oy = fmaxf(oy, 0.f); }
    ((float2*)outbuf)[(size_t)wid * 64 + lane] = make_float2(ox, oy);
}

// ---------------- gather, D=64: one wave per node, 1 float per lane ----------------
template <bool RELU>
__global__ void k_gather64(const int* __restrict__ rowptr, const int* __restrict__ col,
                           const float* __restrict__ dinv, const float* __restrict__ t,
                           const float* __restrict__ b, float* __restrict__ outbuf) {
    unsigned wid = (blockIdx.x * blockDim.x + threadIdx.x) >> 6;
    int lane = threadIdx.x & 63;
    if (wid >= N_NODES) return;
    int beg = rowptr[wid], end = rowptr[wid + 1];
    float acc = t[(size_t)wid * 64 + lane];
    for (int j = beg; j < end; ++j) {
        int s = col[j];
        acc += t[(size_t)s * 64 + lane];          // 256B coalesced row read
    }
    float o = dinv[wid] * acc + b[lane];
    if (RELU) o = fmaxf(o, 0.f);
    outbuf[(size_t)wid * 64 + lane] = o;
}

// ---------------- decode: out[e] = dot(z[a], z[b]) over 64 dims ----------------
__global__ void k_decode(const int* __restrict__ eli, const float* __restrict__ z,
                         float* __restrict__ out) {
    int e = blockIdx.x * blockDim.x + threadIdx.x;
    if (e >= N_EL) return;
    int a = eli[e];
    int b = eli[N_EL + e];
    const float4* za = (const float4*)(z + (size_t)a * 64);
    const float4* zb = (const float4*)(z + (size_t)b * 64);
    float acc = 0.0f;
#pragma unroll
    for (int i = 0; i < 16; ++i) {
        float4 x = za[i], y = zb[i];
        acc += x.x * y.x + x.y * y.y + x.z * y.z + x.w * y.w;
    }
    out[e] = acc;
}

extern "C" void kernel_launch(void* const* d_in, const int* in_sizes, int n_in,
                              void* d_out, int out_size, void* d_ws, size_t ws_size,
                              hipStream_t stream) {
    const float* x   = (const float*)d_in[0];
    const int*   ei  = (const int*)d_in[1];   // [2, E]: src row then dst row
    const int*   eli = (const int*)d_in[2];   // [2, EL]
    const float* W1  = (const float*)d_in[3];
    const float* b1  = (const float*)d_in[4];
    const float* W2  = (const float*)d_in[5];
    const float* b2  = (const float*)d_in[6];
    const float* W3  = (const float*)d_in[7];
    const float* b3  = (const float*)d_in[8];
    float* out = (float*)d_out;

    const int* srcA = ei;
    const int* dstA = ei + N_EDGES;

    // workspace layout (bytes)
    char* ws = (char*)d_ws;
    float* dinv   = (float*)(ws + 0);                 // 400 KB
    int*   degi   = (int*)  (ws + (512u << 10));      // 400 KB
    int*   rowptr = (int*)  (ws + (1024u << 10));     // 400 KB (+4)
    int*   cursor = (int*)  (ws + (1536u << 10));     // 400 KB
    int*   col    = (int*)  (ws + (2048u << 10));     // 6.4 MB
    float* t      = (float*)(ws + (9u << 20));        // 51.2 MB
    float* agg    = (float*)(ws + (61u << 20));       // 51.2 MB  (end ~112.2 MB)

    const int B = 256;
    const int gN   = (N_NODES + B - 1) / B;
    const int gE   = (N_EDGES + B - 1) / B;
    const int gG   = (N_NODES * 64 + B - 1) / B;        // gather: 1 wave/node
    const int gM128 = (N_NODES * 32 + B - 1) / B;       // gemm D=128: N*32 threads
    const int gM64  = (N_NODES * 16 + B - 1) / B;       // gemm D=64
    const int gEL  = (N_EL + B - 1) / B;

    // ---- CSR build (once per call; reused by all 3 layers) ----
    hipMemsetAsync(degi, 0, N_NODES * sizeof(int), stream);
    hipMemsetAsync(cursor, 0, N_NODES * sizeof(int), stream);
    k_hist<<<gE, B, 0, stream>>>(dstA, degi);
    k_dinv<<<gN, B, 0, stream>>>(degi, dinv);
    k_scan_rowptr<<<1, 1024, 0, stream>>>(degi, rowptr);
    k_fill<<<gE, B, 0, stream>>>(srcA, dstA, rowptr, cursor, col);

    // ---- layer 1 ----
    k_gemm4<128><<<gM128, B, 0, stream>>>(x, W1, dinv, t);
    k_gather128<true><<<gG, B, 0, stream>>>(rowptr, col, dinv, t, b1, agg);
    // ---- layer 2 ----
    k_gemm4<128><<<gM128, B, 0, stream>>>(agg, W2, dinv, t);
    k_gather128<true><<<gG, B, 0, stream>>>(rowptr, col, dinv, t, b2, agg);
    // ---- layer 3 ----
    k_gemm4<64><<<gM64, B, 0, stream>>>(agg, W3, dinv, t);
    k_gather64<false><<<gG, B, 0, stream>>>(rowptr, col, dinv, t, b3, agg);

    // ---- decode ----
    k_decode<<<gEL, B, 0, stream>>>(eli, agg, out);
}

// Round 5
// 966.487 us; speedup vs baseline: 8.2201x; 1.5529x over previous
//
#include <hip/hip_runtime.h>
#include <hip/hip_bf16.h>

#define N_NODES 100000
#define N_EDGES 1600000
#define N_EL    200000
// D_IN = D_HID = 128; layer-3 output D = 64. f32 inputs, int32 indices, f32 output.
// Round 5: register-blocked LDS GEMM (64 nodes/block, 8n x 4c per thread) +
//          4x-unrolled pull-gather. CSR pull aggregation, zero atomics in hot path.

// ---------------- degree histogram (int) ----------------
__global__ void k_hist(const int* __restrict__ dst, int* __restrict__ degi) {
    int e = blockIdx.x * blockDim.x + threadIdx.x;
    if (e < N_EDGES) atomicAdd(&degi[dst[e]], 1);
}

__global__ void k_dinv(const int* __restrict__ degi, float* __restrict__ dinv) {
    int i = blockIdx.x * blockDim.x + threadIdx.x;
    if (i < N_NODES) dinv[i] = 1.0f / sqrtf((float)(degi[i] + 1));  // +1 self-loop
}

// ---------------- exclusive scan of degi -> rowptr (single block) ----------------
__global__ void k_scan_rowptr(const int* __restrict__ degi, int* __restrict__ rowptr) {
    const int T = 1024;
    __shared__ int partial[T];
    int tid = threadIdx.x;
    int chunk = (N_NODES + T - 1) / T;
    int start = tid * chunk;
    int end = min(start + chunk, N_NODES);
    int sum = 0;
    for (int i = start; i < end; ++i) sum += degi[i];
    partial[tid] = sum;
    __syncthreads();
    for (int off = 1; off < T; off <<= 1) {
        int v = (tid >= off) ? partial[tid - off] : 0;
        __syncthreads();
        partial[tid] += v;
        __syncthreads();
    }
    int run = (tid == 0) ? 0 : partial[tid - 1];
    for (int i = start; i < end; ++i) {
        rowptr[i] = run;
        run += degi[i];
    }
    if (tid == T - 1) rowptr[N_NODES] = run;
}

// ---------------- CSR fill: col[pos] = src ----------------
__global__ void k_fill(const int* __restrict__ src, const int* __restrict__ dst,
                       const int* __restrict__ rowptr, int* __restrict__ cursor,
                       int* __restrict__ col) {
    int e = blockIdx.x * blockDim.x + threadIdx.x;
    if (e >= N_EDGES) return;
    int d = dst[e];
    int pos = rowptr[d] + atomicAdd(&cursor[d], 1);
    col[pos] = src[e];
}

// ---------------- GEMM: C[n,:] = dinv[n] * (A[n,:128] @ W[128,D]) ----------------
// Block = 256 threads, 64 nodes. W staged in LDS (128*D f32). Thread computes
// NPT nodes x 4 cols with k unrolled by 4. VALU-bound by design.
template <int D>
__global__ __launch_bounds__(256) void k_gemm_lds(const float* __restrict__ A,
        const float* __restrict__ W, const float* __restrict__ dinv,
        float* __restrict__ C) {
    constexpr int CG = D / 4;        // col groups: 32 (D=128) or 16 (D=64)
    constexpr int NG = 256 / CG;     // node groups: 8 or 16
    constexpr int NPT = 64 / NG;     // nodes per thread: 8 or 4
    __shared__ float4 sW4[128 * CG]; // [k][cg] float4  (64 KB or 32 KB)

    int tid = threadIdx.x;
    int cg = tid % CG;
    int ng = tid / CG;
    int n0 = blockIdx.x * 64;

    // stage W
    const float4* W4 = (const float4*)W;
    for (int i = tid; i < 128 * CG; i += 256) sW4[i] = W4[i];
    __syncthreads();

    float4 acc[NPT];
#pragma unroll
    for (int i = 0; i < NPT; ++i) acc[i] = make_float4(0.f, 0.f, 0.f, 0.f);

    const float4* A4 = (const float4*)A;   // [N][32] float4 (K=128 always)

    for (int k4 = 0; k4 < 32; ++k4) {
        float4 av[NPT];
#pragma unroll
        for (int i = 0; i < NPT; ++i) {
            int n = n0 + ng * NPT + i;
            n = min(n, N_NODES - 1);                   // tail-block clamp
            av[i] = A4[(size_t)n * 32 + k4];
        }
        float4 w0 = sW4[(k4 * 4 + 0) * CG + cg];
        float4 w1 = sW4[(k4 * 4 + 1) * CG + cg];
        float4 w2 = sW4[(k4 * 4 + 2) * CG + cg];
        float4 w3 = sW4[(k4 * 4 + 3) * CG + cg];
#pragma unroll
        for (int i = 0; i < NPT; ++i) {
            acc[i].x = fmaf(av[i].x, w0.x, acc[i].x);
            acc[i].y = fmaf(av[i].x, w0.y, acc[i].y);
            acc[i].z = fmaf(av[i].x, w0.z, acc[i].z);
            acc[i].w = fmaf(av[i].x, w0.w, acc[i].w);
            acc[i].x = fmaf(av[i].y, w1.x, acc[i].x);
            acc[i].y = fmaf(av[i].y, w1.y, acc[i].y);
            acc[i].z = fmaf(av[i].y, w1.z, acc[i].z);
            acc[i].w = fmaf(av[i].y, w1.w, acc[i].w);
            acc[i].x = fmaf(av[i].z, w2.x, acc[i].x);
            acc[i].y = fmaf(av[i].z, w2.y, acc[i].y);
            acc[i].z = fmaf(av[i].z, w2.z, acc[i].z);
            acc[i].w = fmaf(av[i].z, w2.w, acc[i].w);
            acc[i].x = fmaf(av[i].w, w3.x, acc[i].x);
            acc[i].y = fmaf(av[i].w, w3.y, acc[i].y);
            acc[i].z = fmaf(av[i].w, w3.z, acc[i].z);
            acc[i].w = fmaf(av[i].w, w3.w, acc[i].w);
        }
    }

#pragma unroll
    for (int i = 0; i < NPT; ++i) {
        int n = n0 + ng * NPT + i;
        if (n < N_NODES) {
            float di = dinv[n];
            float4 o = acc[i];
            o.x *= di; o.y *= di; o.z *= di; o.w *= di;
            ((float4*)C)[(size_t)n * CG + cg] = o;
        }
    }
}

// ---------------- gather, D=128: one wave/node, float2/lane, 4x unroll ----------------
template <bool RELU>
__global__ void k_gather128(const int* __restrict__ rowptr, const int* __restrict__ col,
                            const float* __restrict__ dinv, const float* __restrict__ t,
                            const float* __restrict__ b, float* __restrict__ outbuf) {
    unsigned wid = (blockIdx.x * blockDim.x + threadIdx.x) >> 6;   // node id
    int lane = threadIdx.x & 63;
    if (wid >= N_NODES) return;
    int beg = rowptr[wid], end = rowptr[wid + 1];
    const float2* T2 = (const float2*)t;
    float2 acc = T2[(size_t)wid * 64 + lane];    // self-loop term t'[n]
    int j = beg;
    for (; j + 4 <= end; j += 4) {
        int s0 = col[j], s1 = col[j + 1], s2 = col[j + 2], s3 = col[j + 3];
        float2 v0 = T2[(size_t)s0 * 64 + lane];
        float2 v1 = T2[(size_t)s1 * 64 + lane];
        float2 v2 = T2[(size_t)s2 * 64 + lane];
        float2 v3 = T2[(size_t)s3 * 64 + lane];
        acc.x += v0.x + v1.x + v2.x + v3.x;
        acc.y += v0.y + v1.y + v2.y + v3.y;
    }
    for (; j < end; ++j) {
        int s = col[j];
        float2 v = T2[(size_t)s * 64 + lane];
        acc.x += v.x; acc.y += v.y;
    }
    float di = dinv[wid];
    float2 bb = ((const float2*)b)[lane];
    float ox = di * acc.x + bb.x;
    float oy = di * acc.y + bb.y;
    if (RELU) { ox = fmaxf(ox, 0.f); oy = fmaxf(oy, 0.f); }
    ((float2*)outbuf)[(size_t)wid * 64 + lane] = make_float2(ox, oy);
}

// ---------------- gather, D=64: one wave/node, 1 float/lane, 4x unroll ----------------
template <bool RELU>
__global__ void k_gather64(const int* __restrict__ rowptr, const int* __restrict__ col,
                           const float* __restrict__ dinv, const float* __restrict__ t,
                           const float* __restrict__ b, float* __restrict__ outbuf) {
    unsigned wid = (blockIdx.x * blockDim.x + threadIdx.x) >> 6;
    int lane = threadIdx.x & 63;
    if (wid >= N_NODES) return;
    int beg = rowptr[wid], end = rowptr[wid + 1];
    float acc = t[(size_t)wid * 64 + lane];
    int j = beg;
    for (; j + 4 <= end; j += 4) {
        int s0 = col[j], s1 = col[j + 1], s2 = col[j + 2], s3 = col[j + 3];
        float v0 = t[(size_t)s0 * 64 + lane];
        float v1 = t[(size_t)s1 * 64 + lane];
        float v2 = t[(size_t)s2 * 64 + lane];
        float v3 = t[(size_t)s3 * 64 + lane];
        acc += v0 + v1 + v2 + v3;
    }
    for (; j < end; ++j) acc += t[(size_t)col[j] * 64 + lane];
    float o = dinv[wid] * acc + b[lane];
    if (RELU) o = fmaxf(o, 0.f);
    outbuf[(size_t)wid * 64 + lane] = o;
}

// ---------------- decode: out[e] = dot(z[a], z[b]) over 64 dims ----------------
__global__ void k_decode(const int* __restrict__ eli, const float* __restrict__ z,
                         float* __restrict__ out) {
    int e = blockIdx.x * blockDim.x + threadIdx.x;
    if (e >= N_EL) return;
    int a = eli[e];
    int b = eli[N_EL + e];
    const float4* za = (const float4*)(z + (size_t)a * 64);
    const float4* zb = (const float4*)(z + (size_t)b * 64);
    float acc = 0.0f;
#pragma unroll
    for (int i = 0; i < 16; ++i) {
        float4 x = za[i], y = zb[i];
        acc += x.x * y.x + x.y * y.y + x.z * y.z + x.w * y.w;
    }
    out[e] = acc;
}

extern "C" void kernel_launch(void* const* d_in, const int* in_sizes, int n_in,
                              void* d_out, int out_size, void* d_ws, size_t ws_size,
                              hipStream_t stream) {
    const float* x   = (const float*)d_in[0];
    const int*   ei  = (const int*)d_in[1];   // [2, E]: src row then dst row
    const int*   eli = (const int*)d_in[2];   // [2, EL]
    const float* W1  = (const float*)d_in[3];
    const float* b1  = (const float*)d_in[4];
    const float* W2  = (const float*)d_in[5];
    const float* b2  = (const float*)d_in[6];
    const float* W3  = (const float*)d_in[7];
    const float* b3  = (const float*)d_in[8];
    float* out = (float*)d_out;

    const int* srcA = ei;
    const int* dstA = ei + N_EDGES;

    // workspace layout (bytes)
    char* ws = (char*)d_ws;
    float* dinv   = (float*)(ws + 0);
    int*   degi   = (int*)  (ws + (512u << 10));
    int*   rowptr = (int*)  (ws + (1024u << 10));
    int*   cursor = (int*)  (ws + (1536u << 10));
    int*   col    = (int*)  (ws + (2048u << 10));     // 6.4 MB
    float* t      = (float*)(ws + (9u << 20));        // 51.2 MB
    float* agg    = (float*)(ws + (61u << 20));       // 51.2 MB

    const int B = 256;
    const int gN  = (N_NODES + B - 1) / B;
    const int gE  = (N_EDGES + B - 1) / B;
    const int gG  = (N_NODES * 64 + B - 1) / B;       // gather: 1 wave/node
    const int gT  = (N_NODES + 63) / 64;              // gemm: 64 nodes/block
    const int gEL = (N_EL + B - 1) / B;

    // ---- CSR build ----
    hipMemsetAsync(degi, 0, N_NODES * sizeof(int), stream);
    hipMemsetAsync(cursor, 0, N_NODES * sizeof(int), stream);
    k_hist<<<gE, B, 0, stream>>>(dstA, degi);
    k_dinv<<<gN, B, 0, stream>>>(degi, dinv);
    k_scan_rowptr<<<1, 1024, 0, stream>>>(degi, rowptr);
    k_fill<<<gE, B, 0, stream>>>(srcA, dstA, rowptr, cursor, col);

    // ---- layer 1 ----
    k_gemm_lds<128><<<gT, B, 0, stream>>>(x, W1, dinv, t);
    k_gather128<true><<<gG, B, 0, stream>>>(rowptr, col, dinv, t, b1, agg);
    // ---- layer 2 ----
    k_gemm_lds<128><<<gT, B, 0, stream>>>(agg, W2, dinv, t);
    k_gather128<true><<<gG, B, 0, stream>>>(rowptr, col, dinv, t, b2, agg);
    // ---- layer 3 ----
    k_gemm_lds<64><<<gT, B, 0, stream>>>(agg, W3, dinv, t);
    k_gather64<false><<<gG, B, 0, stream>>>(rowptr, col, dinv, t, b3, agg);

    // ---- decode ----
    k_decode<<<gEL, B, 0, stream>>>(eli, agg, out);
}

// Round 7
// 790.451 us; speedup vs baseline: 10.0507x; 1.2227x over previous
//
#include <hip/hip_runtime.h>
#include <hip/hip_bf16.h>

#define N_NODES 100000
#define N_EDGES 1600000
#define N_EL    200000
// D_IN = D_HID = 128; layer-3 output D = 64. f32 inputs, int32 indices, f32 output.
// Round 7: fix workspace overlap (bsum/boff were inside cursor's region ->
// corrupted CSR fill -> poisoned col -> wild gather address -> GPU fault).
// Scan logic and 8x gather unroll unchanged from round 6.

#define NB_SCAN ((N_NODES + 255) / 256)   // 391

// ---------------- degree histogram (int) ----------------
__global__ void k_hist(const int* __restrict__ dst, int* __restrict__ degi) {
    int e = blockIdx.x * blockDim.x + threadIdx.x;
    if (e < N_EDGES) atomicAdd(&degi[dst[e]], 1);
}

__global__ void k_dinv(const int* __restrict__ degi, float* __restrict__ dinv) {
    int i = blockIdx.x * blockDim.x + threadIdx.x;
    if (i < N_NODES) dinv[i] = 1.0f / sqrtf((float)(degi[i] + 1));  // +1 self-loop
}

// ---------------- multi-block exclusive scan: degi -> rowptr ----------------
__global__ void k_scan1(const int* __restrict__ degi, int* __restrict__ rowptr,
                        int* __restrict__ bsum) {
    __shared__ int s[256];
    int t = threadIdx.x;
    int i = blockIdx.x * 256 + t;
    int v = (i < N_NODES) ? degi[i] : 0;
    s[t] = v;
    __syncthreads();
    for (int off = 1; off < 256; off <<= 1) {
        int u = (t >= off) ? s[t - off] : 0;
        __syncthreads();
        s[t] += u;
        __syncthreads();
    }
    if (i < N_NODES) rowptr[i] = s[t] - v;          // exclusive, local
    if (t == 255) bsum[blockIdx.x] = s[255];
}

__global__ void k_scan2(const int* __restrict__ bsum, int* __restrict__ boff) {
    __shared__ int s[512];
    int t = threadIdx.x;
    int v = (t < NB_SCAN) ? bsum[t] : 0;
    s[t] = v;
    __syncthreads();
    for (int off = 1; off < 512; off <<= 1) {
        int u = (t >= off) ? s[t - off] : 0;
        __syncthreads();
        s[t] += u;
        __syncthreads();
    }
    if (t < NB_SCAN) boff[t] = s[t] - v;            // exclusive
    if (t == NB_SCAN - 1) boff[NB_SCAN] = s[t];     // total
}

__global__ void k_scan3(int* __restrict__ rowptr, const int* __restrict__ boff) {
    int i = blockIdx.x * 256 + threadIdx.x;
    if (i < N_NODES) rowptr[i] += boff[blockIdx.x];
    if (i == 0) rowptr[N_NODES] = boff[NB_SCAN];
}

// ---------------- CSR fill: col[pos] = src ----------------
__global__ void k_fill(const int* __restrict__ src, const int* __restrict__ dst,
                       const int* __restrict__ rowptr, int* __restrict__ cursor,
                       int* __restrict__ col) {
    int e = blockIdx.x * blockDim.x + threadIdx.x;
    if (e >= N_EDGES) return;
    int d = dst[e];
    int pos = rowptr[d] + atomicAdd(&cursor[d], 1);
    col[pos] = src[e];
}

// ---------------- GEMM: C[n,:] = dinv[n] * (A[n,:128] @ W[128,D]) ----------------
template <int D>
__global__ __launch_bounds__(256) void k_gemm_lds(const float* __restrict__ A,
        const float* __restrict__ W, const float* __restrict__ dinv,
        float* __restrict__ C) {
    constexpr int CG = D / 4;
    constexpr int NG = 256 / CG;
    constexpr int NPT = 64 / NG;
    __shared__ float4 sW4[128 * CG];

    int tid = threadIdx.x;
    int cg = tid % CG;
    int ng = tid / CG;
    int n0 = blockIdx.x * 64;

    const float4* W4 = (const float4*)W;
    for (int i = tid; i < 128 * CG; i += 256) sW4[i] = W4[i];
    __syncthreads();

    float4 acc[NPT];
#pragma unroll
    for (int i = 0; i < NPT; ++i) acc[i] = make_float4(0.f, 0.f, 0.f, 0.f);

    const float4* A4 = (const float4*)A;

    for (int k4 = 0; k4 < 32; ++k4) {
        float4 av[NPT];
#pragma unroll
        for (int i = 0; i < NPT; ++i) {
            int n = n0 + ng * NPT + i;
            n = min(n, N_NODES - 1);
            av[i] = A4[(size_t)n * 32 + k4];
        }
        float4 w0 = sW4[(k4 * 4 + 0) * CG + cg];
        float4 w1 = sW4[(k4 * 4 + 1) * CG + cg];
        float4 w2 = sW4[(k4 * 4 + 2) * CG + cg];
        float4 w3 = sW4[(k4 * 4 + 3) * CG + cg];
#pragma unroll
        for (int i = 0; i < NPT; ++i) {
            acc[i].x = fmaf(av[i].x, w0.x, acc[i].x);
            acc[i].y = fmaf(av[i].x, w0.y, acc[i].y);
            acc[i].z = fmaf(av[i].x, w0.z, acc[i].z);
            acc[i].w = fmaf(av[i].x, w0.w, acc[i].w);
            acc[i].x = fmaf(av[i].y, w1.x, acc[i].x);
            acc[i].y = fmaf(av[i].y, w1.y, acc[i].y);
            acc[i].z = fmaf(av[i].y, w1.z, acc[i].z);
            acc[i].w = fmaf(av[i].y, w1.w, acc[i].w);
            acc[i].x = fmaf(av[i].z, w2.x, acc[i].x);
            acc[i].y = fmaf(av[i].z, w2.y, acc[i].y);
            acc[i].z = fmaf(av[i].z, w2.z, acc[i].z);
            acc[i].w = fmaf(av[i].z, w2.w, acc[i].w);
            acc[i].x = fmaf(av[i].w, w3.x, acc[i].x);
            acc[i].y = fmaf(av[i].w, w3.y, acc[i].y);
            acc[i].z = fmaf(av[i].w, w3.z, acc[i].z);
            acc[i].w = fmaf(av[i].w, w3.w, acc[i].w);
        }
    }

#pragma unroll
    for (int i = 0; i < NPT; ++i) {
        int n = n0 + ng * NPT + i;
        if (n < N_NODES) {
            float di = dinv[n];
            float4 o = acc[i];
            o.x *= di; o.y *= di; o.z *= di; o.w *= di;
            ((float4*)C)[(size_t)n * CG + cg] = o;
        }
    }
}

// ---------------- gather, D=128: one wave/node, float2/lane, 8x unroll ----------------
template <bool RELU>
__global__ void k_gather128(const int* __restrict__ rowptr, const int* __restrict__ col,
                            const float* __restrict__ dinv, const float* __restrict__ t,
                            const float* __restrict__ b, float* __restrict__ outbuf) {
    unsigned wid = (blockIdx.x * blockDim.x + threadIdx.x) >> 6;
    int lane = threadIdx.x & 63;
    if (wid >= N_NODES) return;
    int beg = rowptr[wid], end = rowptr[wid + 1];
    const float2* T2 = (const float2*)t;
    float2 acc = T2[(size_t)wid * 64 + lane];    // self-loop term
    int j = beg;
    for (; j + 8 <= end; j += 8) {
        int s0 = col[j], s1 = col[j+1], s2 = col[j+2], s3 = col[j+3];
        int s4 = col[j+4], s5 = col[j+5], s6 = col[j+6], s7 = col[j+7];
        float2 v0 = T2[(size_t)s0 * 64 + lane];
        float2 v1 = T2[(size_t)s1 * 64 + lane];
        float2 v2 = T2[(size_t)s2 * 64 + lane];
        float2 v3 = T2[(size_t)s3 * 64 + lane];
        float2 v4 = T2[(size_t)s4 * 64 + lane];
        float2 v5 = T2[(size_t)s5 * 64 + lane];
        float2 v6 = T2[(size_t)s6 * 64 + lane];
        float2 v7 = T2[(size_t)s7 * 64 + lane];
        acc.x += (v0.x + v1.x) + (v2.x + v3.x) + ((v4.x + v5.x) + (v6.x + v7.x));
        acc.y += (v0.y + v1.y) + (v2.y + v3.y) + ((v4.y + v5.y) + (v6.y + v7.y));
    }
    for (; j + 4 <= end; j += 4) {
        int s0 = col[j], s1 = col[j+1], s2 = col[j+2], s3 = col[j+3];
        float2 v0 = T2[(size_t)s0 * 64 + lane];
        float2 v1 = T2[(size_t)s1 * 64 + lane];
        float2 v2 = T2[(size_t)s2 * 64 + lane];
        float2 v3 = T2[(size_t)s3 * 64 + lane];
        acc.x += (v0.x + v1.x) + (v2.x + v3.x);
        acc.y += (v0.y + v1.y) + (v2.y + v3.y);
    }
    for (; j < end; ++j) {
        int s = col[j];
        float2 v = T2[(size_t)s * 64 + lane];
        acc.x += v.x; acc.y += v.y;
    }
    float di = dinv[wid];
    float2 bb = ((const float2*)b)[lane];
    float ox = di * acc.x + bb.x;
    float oy = di * acc.y + bb.y;
    if (RELU) { ox = fmaxf(ox, 0.f); oy = fmaxf(oy, 0.f); }
    ((float2*)outbuf)[(size_t)wid * 64 + lane] = make_float2(ox, oy);
}

// ---------------- gather, D=64: one wave/node, 1 float/lane, 8x unroll ----------------
template <bool RELU>
__global__ void k_gather64(const int* __restrict__ rowptr, const int* __restrict__ col,
                           const float* __restrict__ dinv, const float* __restrict__ t,
                           const float* __restrict__ b, float* __restrict__ outbuf) {
    unsigned wid = (blockIdx.x * blockDim.x + threadIdx.x) >> 6;
    int lane = threadIdx.x & 63;
    if (wid >= N_NODES) return;
    int beg = rowptr[wid], end = rowptr[wid + 1];
    float acc = t[(size_t)wid * 64 + lane];
    int j = beg;
    for (; j + 8 <= end; j += 8) {
        int s0 = col[j], s1 = col[j+1], s2 = col[j+2], s3 = col[j+3];
        int s4 = col[j+4], s5 = col[j+5], s6 = col[j+6], s7 = col[j+7];
        float v0 = t[(size_t)s0 * 64 + lane];
        float v1 = t[(size_t)s1 * 64 + lane];
        float v2 = t[(size_t)s2 * 64 + lane];
        float v3 = t[(size_t)s3 * 64 + lane];
        float v4 = t[(size_t)s4 * 64 + lane];
        float v5 = t[(size_t)s5 * 64 + lane];
        float v6 = t[(size_t)s6 * 64 + lane];
        float v7 = t[(size_t)s7 * 64 + lane];
        acc += (v0 + v1) + (v2 + v3) + ((v4 + v5) + (v6 + v7));
    }
    for (; j + 4 <= end; j += 4) {
        int s0 = col[j], s1 = col[j+1], s2 = col[j+2], s3 = col[j+3];
        acc += (t[(size_t)s0 * 64 + lane] + t[(size_t)s1 * 64 + lane])
             + (t[(size_t)s2 * 64 + lane] + t[(size_t)s3 * 64 + lane]);
    }
    for (; j < end; ++j) acc += t[(size_t)col[j] * 64 + lane];
    float o = dinv[wid] * acc + b[lane];
    if (RELU) o = fmaxf(o, 0.f);
    outbuf[(size_t)wid * 64 + lane] = o;
}

// ---------------- decode ----------------
__global__ void k_decode(const int* __restrict__ eli, const float* __restrict__ z,
                         float* __restrict__ out) {
    int e = blockIdx.x * blockDim.x + threadIdx.x;
    if (e >= N_EL) return;
    int a = eli[e];
    int b = eli[N_EL + e];
    const float4* za = (const float4*)(z + (size_t)a * 64);
    const float4* zb = (const float4*)(z + (size_t)b * 64);
    float acc = 0.0f;
#pragma unroll
    for (int i = 0; i < 16; ++i) {
        float4 x = za[i], y = zb[i];
        acc += x.x * y.x + x.y * y.y + x.z * y.z + x.w * y.w;
    }
    out[e] = acc;
}

extern "C" void kernel_launch(void* const* d_in, const int* in_sizes, int n_in,
                              void* d_out, int out_size, void* d_ws, size_t ws_size,
                              hipStream_t stream) {
    const float* x   = (const float*)d_in[0];
    const int*   ei  = (const int*)d_in[1];
    const int*   eli = (const int*)d_in[2];
    const float* W1  = (const float*)d_in[3];
    const float* b1  = (const float*)d_in[4];
    const float* W2  = (const float*)d_in[5];
    const float* b2  = (const float*)d_in[6];
    const float* W3  = (const float*)d_in[7];
    const float* b3  = (const float*)d_in[8];
    float* out = (float*)d_out;

    const int* srcA = ei;
    const int* dstA = ei + N_EDGES;

    // workspace layout (bytes) — regions verified non-overlapping:
    //   dinv   [0,          400,000)
    //   degi   [524,288,    924,288)
    //   rowptr [1,048,576,  1,448,580)
    //   cursor [1,507,328,  1,907,328)
    //   bsum   [1,933,312,  1,934,876)   (ws + 1888 KB)
    //   boff   [1,941,504,  1,943,072)   (ws + 1896 KB)
    //   col    [2,097,152,  8,497,152)
    //   t      [ws + 9 MB,  +51.2 MB)
    //   agg    [ws + 61 MB, +51.2 MB)
    char* ws = (char*)d_ws;
    float* dinv   = (float*)(ws + 0);
    int*   degi   = (int*)  (ws + (512u << 10));
    int*   rowptr = (int*)  (ws + (1024u << 10));
    int*   cursor = (int*)  (ws + (1472u << 10));
    int*   bsum   = (int*)  (ws + (1888u << 10));
    int*   boff   = (int*)  (ws + (1896u << 10));
    int*   col    = (int*)  (ws + (2048u << 10));
    float* t      = (float*)(ws + (9u << 20));
    float* agg    = (float*)(ws + (61u << 20));

    const int B = 256;
    const int gN  = (N_NODES + B - 1) / B;
    const int gE  = (N_EDGES + B - 1) / B;
    const int gG  = (N_NODES * 64 + B - 1) / B;
    const int gT  = (N_NODES + 63) / 64;
    const int gEL = (N_EL + B - 1) / B;

    // ---- CSR build ----
    hipMemsetAsync(degi, 0, N_NODES * sizeof(int), stream);
    hipMemsetAsync(cursor, 0, N_NODES * sizeof(int), stream);
    k_hist<<<gE, B, 0, stream>>>(dstA, degi);
    k_dinv<<<gN, B, 0, stream>>>(degi, dinv);
    k_scan1<<<NB_SCAN, 256, 0, stream>>>(degi, rowptr, bsum);
    k_scan2<<<1, 512, 0, stream>>>(bsum, boff);
    k_scan3<<<NB_SCAN, 256, 0, stream>>>(rowptr, boff);
    k_fill<<<gE, B, 0, stream>>>(srcA, dstA, rowptr, cursor, col);

    // ---- layer 1 ----
    k_gemm_lds<128><<<gT, B, 0, stream>>>(x, W1, dinv, t);
    k_gather128<true><<<gG, B, 0, stream>>>(rowptr, col, dinv, t, b1, agg);
    // ---- layer 2 ----
    k_gemm_lds<128><<<gT, B, 0, stream>>>(agg, W2, dinv, t);
    k_gather128<true><<<gG, B, 0, stream>>>(rowptr, col, dinv, t, b2, agg);
    // ---- layer 3 ----
    k_gemm_lds<64><<<gT, B, 0, stream>>>(agg, W3, dinv, t);
    k_gather64<false><<<gG, B, 0, stream>>>(rowptr, col, dinv, t, b3, agg);

    // ---- decode ----
    k_decode<<<gEL, B, 0, stream>>>(eli, agg, out);
}

// Round 8
// 686.268 us; speedup vs baseline: 11.5766x; 1.1518x over previous
//
#include <hip/hip_runtime.h>
#include <hip/hip_bf16.h>

#define N_NODES 100000
#define N_EDGES 1600000
#define N_EL    200000
// D_IN = D_HID = 128; layer-3 output D = 64. f32 inputs, int32 indices, f32 output.
// Round 8: t (GEMM->gather intermediate) stored as bf16 => gather read traffic halves.
// agg stays f32 (GEMM input / decode input unchanged). dinv folded into scan1.

#define NB_SCAN ((N_NODES + 255) / 256)   // 391

typedef unsigned int uint32;
typedef unsigned short ushort16;

static __device__ __forceinline__ ushort16 f2bf(float f) {
    uint32 u = __float_as_uint(f);
    u += 0x7fffu + ((u >> 16) & 1u);      // RNE
    return (ushort16)(u >> 16);
}
static __device__ __forceinline__ float bf_lo(uint32 p) { return __uint_as_float(p << 16); }
static __device__ __forceinline__ float bf_hi(uint32 p) { return __uint_as_float(p & 0xffff0000u); }
static __device__ __forceinline__ float bf2f(ushort16 h) { return __uint_as_float((uint32)h << 16); }

// ---------------- degree histogram (int) ----------------
__global__ void k_hist(const int* __restrict__ dst, int* __restrict__ degi) {
    int e = blockIdx.x * blockDim.x + threadIdx.x;
    if (e < N_EDGES) atomicAdd(&degi[dst[e]], 1);
}

// ---------------- scan pass 1 (+ dinv) ----------------
__global__ void k_scan1(const int* __restrict__ degi, int* __restrict__ rowptr,
                        int* __restrict__ bsum, float* __restrict__ dinv) {
    __shared__ int s[256];
    int t = threadIdx.x;
    int i = blockIdx.x * 256 + t;
    int v = (i < N_NODES) ? degi[i] : 0;
    if (i < N_NODES) dinv[i] = 1.0f / sqrtf((float)(v + 1));   // +1 self-loop
    s[t] = v;
    __syncthreads();
    for (int off = 1; off < 256; off <<= 1) {
        int u = (t >= off) ? s[t - off] : 0;
        __syncthreads();
        s[t] += u;
        __syncthreads();
    }
    if (i < N_NODES) rowptr[i] = s[t] - v;          // exclusive, local
    if (t == 255) bsum[blockIdx.x] = s[255];
}

__global__ void k_scan2(const int* __restrict__ bsum, int* __restrict__ boff) {
    __shared__ int s[512];
    int t = threadIdx.x;
    int v = (t < NB_SCAN) ? bsum[t] : 0;
    s[t] = v;
    __syncthreads();
    for (int off = 1; off < 512; off <<= 1) {
        int u = (t >= off) ? s[t - off] : 0;
        __syncthreads();
        s[t] += u;
        __syncthreads();
    }
    if (t < NB_SCAN) boff[t] = s[t] - v;            // exclusive
    if (t == NB_SCAN - 1) boff[NB_SCAN] = s[t];     // total
}

__global__ void k_scan3(int* __restrict__ rowptr, const int* __restrict__ boff) {
    int i = blockIdx.x * 256 + threadIdx.x;
    if (i < N_NODES) rowptr[i] += boff[blockIdx.x];
    if (i == 0) rowptr[N_NODES] = boff[NB_SCAN];
}

// ---------------- CSR fill: col[pos] = src ----------------
__global__ void k_fill(const int* __restrict__ src, const int* __restrict__ dst,
                       const int* __restrict__ rowptr, int* __restrict__ cursor,
                       int* __restrict__ col) {
    int e = blockIdx.x * blockDim.x + threadIdx.x;
    if (e >= N_EDGES) return;
    int d = dst[e];
    int pos = rowptr[d] + atomicAdd(&cursor[d], 1);
    col[pos] = src[e];
}

// ---------------- GEMM: C[n,:] = bf16( dinv[n] * (A[n,:128] @ W[128,D]) ) ----------------
template <int D>
__global__ __launch_bounds__(256) void k_gemm_lds(const float* __restrict__ A,
        const float* __restrict__ W, const float* __restrict__ dinv,
        ushort16* __restrict__ C) {
    constexpr int CG = D / 4;
    constexpr int NG = 256 / CG;
    constexpr int NPT = 64 / NG;
    __shared__ float4 sW4[128 * CG];

    int tid = threadIdx.x;
    int cg = tid % CG;
    int ng = tid / CG;
    int n0 = blockIdx.x * 64;

    const float4* W4 = (const float4*)W;
    for (int i = tid; i < 128 * CG; i += 256) sW4[i] = W4[i];
    __syncthreads();

    float4 acc[NPT];
#pragma unroll
    for (int i = 0; i < NPT; ++i) acc[i] = make_float4(0.f, 0.f, 0.f, 0.f);

    const float4* A4 = (const float4*)A;

    for (int k4 = 0; k4 < 32; ++k4) {
        float4 av[NPT];
#pragma unroll
        for (int i = 0; i < NPT; ++i) {
            int n = n0 + ng * NPT + i;
            n = min(n, N_NODES - 1);
            av[i] = A4[(size_t)n * 32 + k4];
        }
        float4 w0 = sW4[(k4 * 4 + 0) * CG + cg];
        float4 w1 = sW4[(k4 * 4 + 1) * CG + cg];
        float4 w2 = sW4[(k4 * 4 + 2) * CG + cg];
        float4 w3 = sW4[(k4 * 4 + 3) * CG + cg];
#pragma unroll
        for (int i = 0; i < NPT; ++i) {
            acc[i].x = fmaf(av[i].x, w0.x, acc[i].x);
            acc[i].y = fmaf(av[i].x, w0.y, acc[i].y);
            acc[i].z = fmaf(av[i].x, w0.z, acc[i].z);
            acc[i].w = fmaf(av[i].x, w0.w, acc[i].w);
            acc[i].x = fmaf(av[i].y, w1.x, acc[i].x);
            acc[i].y = fmaf(av[i].y, w1.y, acc[i].y);
            acc[i].z = fmaf(av[i].y, w1.z, acc[i].z);
            acc[i].w = fmaf(av[i].y, w1.w, acc[i].w);
            acc[i].x = fmaf(av[i].z, w2.x, acc[i].x);
            acc[i].y = fmaf(av[i].z, w2.y, acc[i].y);
            acc[i].z = fmaf(av[i].z, w2.z, acc[i].z);
            acc[i].w = fmaf(av[i].z, w2.w, acc[i].w);
            acc[i].x = fmaf(av[i].w, w3.x, acc[i].x);
            acc[i].y = fmaf(av[i].w, w3.y, acc[i].y);
            acc[i].z = fmaf(av[i].w, w3.z, acc[i].z);
            acc[i].w = fmaf(av[i].w, w3.w, acc[i].w);
        }
    }

#pragma unroll
    for (int i = 0; i < NPT; ++i) {
        int n = n0 + ng * NPT + i;
        if (n < N_NODES) {
            float di = dinv[n];
            float4 o = acc[i];
            // pack 4 bf16 cols (4cg..4cg+3) into one uint2
            uint32 p0 = (uint32)f2bf(o.x * di) | ((uint32)f2bf(o.y * di) << 16);
            uint32 p1 = (uint32)f2bf(o.z * di) | ((uint32)f2bf(o.w * di) << 16);
            uint2 pk; pk.x = p0; pk.y = p1;
            ((uint2*)C)[(size_t)n * (CG) + cg] = pk;   // row = CG uint2 = D bf16
        }
    }
}

// ---------------- gather, D=128: one wave/node, 1 bf162(uint)/lane, 8x unroll ----------------
template <bool RELU>
__global__ void k_gather128(const int* __restrict__ rowptr, const int* __restrict__ col,
                            const float* __restrict__ dinv, const uint32* __restrict__ t,
                            const float* __restrict__ b, float* __restrict__ outbuf) {
    unsigned wid = (blockIdx.x * blockDim.x + threadIdx.x) >> 6;
    int lane = threadIdx.x & 63;
    if (wid >= N_NODES) return;
    int beg = rowptr[wid], end = rowptr[wid + 1];
    uint32 p = t[(size_t)wid * 64 + lane];           // self-loop term (cols 2l, 2l+1)
    float ax = bf_lo(p), ay = bf_hi(p);
    int j = beg;
    for (; j + 8 <= end; j += 8) {
        int s0 = col[j], s1 = col[j+1], s2 = col[j+2], s3 = col[j+3];
        int s4 = col[j+4], s5 = col[j+5], s6 = col[j+6], s7 = col[j+7];
        uint32 v0 = t[(size_t)s0 * 64 + lane];
        uint32 v1 = t[(size_t)s1 * 64 + lane];
        uint32 v2 = t[(size_t)s2 * 64 + lane];
        uint32 v3 = t[(size_t)s3 * 64 + lane];
        uint32 v4 = t[(size_t)s4 * 64 + lane];
        uint32 v5 = t[(size_t)s5 * 64 + lane];
        uint32 v6 = t[(size_t)s6 * 64 + lane];
        uint32 v7 = t[(size_t)s7 * 64 + lane];
        ax += (bf_lo(v0) + bf_lo(v1)) + (bf_lo(v2) + bf_lo(v3))
            + ((bf_lo(v4) + bf_lo(v5)) + (bf_lo(v6) + bf_lo(v7)));
        ay += (bf_hi(v0) + bf_hi(v1)) + (bf_hi(v2) + bf_hi(v3))
            + ((bf_hi(v4) + bf_hi(v5)) + (bf_hi(v6) + bf_hi(v7)));
    }
    for (; j + 4 <= end; j += 4) {
        int s0 = col[j], s1 = col[j+1], s2 = col[j+2], s3 = col[j+3];
        uint32 v0 = t[(size_t)s0 * 64 + lane];
        uint32 v1 = t[(size_t)s1 * 64 + lane];
        uint32 v2 = t[(size_t)s2 * 64 + lane];
        uint32 v3 = t[(size_t)s3 * 64 + lane];
        ax += (bf_lo(v0) + bf_lo(v1)) + (bf_lo(v2) + bf_lo(v3));
        ay += (bf_hi(v0) + bf_hi(v1)) + (bf_hi(v2) + bf_hi(v3));
    }
    for (; j < end; ++j) {
        uint32 v = t[(size_t)col[j] * 64 + lane];
        ax += bf_lo(v); ay += bf_hi(v);
    }
    float di = dinv[wid];
    float2 bb = ((const float2*)b)[lane];
    float ox = di * ax + bb.x;
    float oy = di * ay + bb.y;
    if (RELU) { ox = fmaxf(ox, 0.f); oy = fmaxf(oy, 0.f); }
    ((float2*)outbuf)[(size_t)wid * 64 + lane] = make_float2(ox, oy);
}

// ---------------- gather, D=64: one wave/node, 1 bf16(ushort)/lane, 8x unroll ----------------
template <bool RELU>
__global__ void k_gather64(const int* __restrict__ rowptr, const int* __restrict__ col,
                           const float* __restrict__ dinv, const ushort16* __restrict__ t,
                           const float* __restrict__ b, float* __restrict__ outbuf) {
    unsigned wid = (blockIdx.x * blockDim.x + threadIdx.x) >> 6;
    int lane = threadIdx.x & 63;
    if (wid >= N_NODES) return;
    int beg = rowptr[wid], end = rowptr[wid + 1];
    float acc = bf2f(t[(size_t)wid * 64 + lane]);
    int j = beg;
    for (; j + 8 <= end; j += 8) {
        int s0 = col[j], s1 = col[j+1], s2 = col[j+2], s3 = col[j+3];
        int s4 = col[j+4], s5 = col[j+5], s6 = col[j+6], s7 = col[j+7];
        float v0 = bf2f(t[(size_t)s0 * 64 + lane]);
        float v1 = bf2f(t[(size_t)s1 * 64 + lane]);
        float v2 = bf2f(t[(size_t)s2 * 64 + lane]);
        float v3 = bf2f(t[(size_t)s3 * 64 + lane]);
        float v4 = bf2f(t[(size_t)s4 * 64 + lane]);
        float v5 = bf2f(t[(size_t)s5 * 64 + lane]);
        float v6 = bf2f(t[(size_t)s6 * 64 + lane]);
        float v7 = bf2f(t[(size_t)s7 * 64 + lane]);
        acc += (v0 + v1) + (v2 + v3) + ((v4 + v5) + (v6 + v7));
    }
    for (; j + 4 <= end; j += 4) {
        int s0 = col[j], s1 = col[j+1], s2 = col[j+2], s3 = col[j+3];
        acc += (bf2f(t[(size_t)s0 * 64 + lane]) + bf2f(t[(size_t)s1 * 64 + lane]))
             + (bf2f(t[(size_t)s2 * 64 + lane]) + bf2f(t[(size_t)s3 * 64 + lane]));
    }
    for (; j < end; ++j) acc += bf2f(t[(size_t)col[j] * 64 + lane]);
    float o = dinv[wid] * acc + b[lane];
    if (RELU) o = fmaxf(o, 0.f);
    outbuf[(size_t)wid * 64 + lane] = o;
}

// ---------------- decode (agg/z stays f32) ----------------
__global__ void k_decode(const int* __restrict__ eli, const float* __restrict__ z,
                         float* __restrict__ out) {
    int e = blockIdx.x * blockDim.x + threadIdx.x;
    if (e >= N_EL) return;
    int a = eli[e];
    int b = eli[N_EL + e];
    const float4* za = (const float4*)(z + (size_t)a * 64);
    const float4* zb = (const float4*)(z + (size_t)b * 64);
    float acc = 0.0f;
#pragma unroll
    for (int i = 0; i < 16; ++i) {
        float4 x = za[i], y = zb[i];
        acc += x.x * y.x + x.y * y.y + x.z * y.z + x.w * y.w;
    }
    out[e] = acc;
}

extern "C" void kernel_launch(void* const* d_in, const int* in_sizes, int n_in,
                              void* d_out, int out_size, void* d_ws, size_t ws_size,
                              hipStream_t stream) {
    const float* x   = (const float*)d_in[0];
    const int*   ei  = (const int*)d_in[1];
    const int*   eli = (const int*)d_in[2];
    const float* W1  = (const float*)d_in[3];
    const float* b1  = (const float*)d_in[4];
    const float* W2  = (const float*)d_in[5];
    const float* b2  = (const float*)d_in[6];
    const float* W3  = (const float*)d_in[7];
    const float* b3  = (const float*)d_in[8];
    float* out = (float*)d_out;

    const int* srcA = ei;
    const int* dstA = ei + N_EDGES;

    // workspace layout (bytes) — non-overlapping:
    //   dinv   [0,          400,000)
    //   degi   [524,288,    924,288)
    //   rowptr [1,048,576,  1,448,580)
    //   cursor [1,507,328,  1,907,328)
    //   bsum   [1,933,312,  1,934,876)
    //   boff   [1,941,504,  1,943,072)
    //   col    [2,097,152,  8,497,152)
    //   t      [ws + 9 MB,  +25.6 MB)   bf16 N x 128
    //   agg    [ws + 40 MB, +51.2 MB)   f32  N x 128
    char* ws = (char*)d_ws;
    float*    dinv   = (float*)   (ws + 0);
    int*      degi   = (int*)     (ws + (512u << 10));
    int*      rowptr = (int*)     (ws + (1024u << 10));
    int*      cursor = (int*)     (ws + (1472u << 10));
    int*      bsum   = (int*)     (ws + (1888u << 10));
    int*      boff   = (int*)     (ws + (1896u << 10));
    int*      col    = (int*)     (ws + (2048u << 10));
    ushort16* t      = (ushort16*)(ws + (9u << 20));
    float*    agg    = (float*)   (ws + (40u << 20));

    const int B = 256;
    const int gN  = (N_NODES + B - 1) / B;
    const int gE  = (N_EDGES + B - 1) / B;
    const int gG  = (N_NODES * 64 + B - 1) / B;
    const int gT  = (N_NODES + 63) / 64;
    const int gEL = (N_EL + B - 1) / B;

    // ---- CSR build ----
    hipMemsetAsync(degi, 0, N_NODES * sizeof(int), stream);
    hipMemsetAsync(cursor, 0, N_NODES * sizeof(int), stream);
    k_hist<<<gE, B, 0, stream>>>(dstA, degi);
    k_scan1<<<NB_SCAN, 256, 0, stream>>>(degi, rowptr, bsum, dinv);
    k_scan2<<<1, 512, 0, stream>>>(bsum, boff);
    k_scan3<<<NB_SCAN, 256, 0, stream>>>(rowptr, boff);
    k_fill<<<gE, B, 0, stream>>>(srcA, dstA, rowptr, cursor, col);

    // ---- layer 1 ----
    k_gemm_lds<128><<<gT, B, 0, stream>>>(x, W1, dinv, t);
    k_gather128<true><<<gG, B, 0, stream>>>(rowptr, col, dinv, (const uint32*)t, b1, agg);
    // ---- layer 2 ----
    k_gemm_lds<128><<<gT, B, 0, stream>>>(agg, W2, dinv, t);
    k_gather128<true><<<gG, B, 0, stream>>>(rowptr, col, dinv, (const uint32*)t, b2, agg);
    // ---- layer 3 ----
    k_gemm_lds<64><<<gT, B, 0, stream>>>(agg, W3, dinv, t);
    k_gather64<false><<<gG, B, 0, stream>>>(rowptr, col, dinv, t, b3, agg);

    // ---- decode ----
    k_decode<<<gEL, B, 0, stream>>>(eli, agg, out);
}